// Round 10
// baseline (47.304 us; speedup 1.0000x reference)
//
#include <hip/hip_runtime.h>

typedef unsigned short u16;
typedef __attribute__((ext_vector_type(4))) unsigned short u16x4;
typedef __attribute__((ext_vector_type(8))) unsigned short u16x8;
typedef __attribute__((ext_vector_type(8))) short bf16x8;
typedef __attribute__((ext_vector_type(4))) float f32x4;

#define QN 512
#define SN 128
#define DN 512
#define QT 8192   /* query frames */
#define STF 2048  /* support frames */

#if __has_builtin(__builtin_amdgcn_exp2f)
#define EXP2F __builtin_amdgcn_exp2f
#else
#define EXP2F exp2f
#endif
#if __has_builtin(__builtin_amdgcn_logf)
#define LOG2F __builtin_amdgcn_logf
#else
#define LOG2F log2f
#endif

#define KEXP 2.8853900817779268f   /* 1/(lbda*ln2), lbda=0.5 */
#define CLOG 0.34657359027997264f  /* lbda*ln2 */
#define K2   7.38905609893065f     /* exp(1/lbda) = e^2 */

__device__ __forceinline__ u16 f2bf(float f){
  union { float f; unsigned int u; } v; v.f = f;
  unsigned int u = v.u;
  unsigned int r = (u + 0x7fffu + ((u >> 16) & 1u)) >> 16;
  return (u16)r;
}
__device__ __forceinline__ float bf2f(u16 v){
  union { unsigned int u; float f; } x; x.u = ((unsigned int)v) << 16; return x.f;
}

__device__ __forceinline__ void gld16(const void* g, unsigned lds_addr){
  __builtin_amdgcn_global_load_lds(
      (const __attribute__((address_space(1))) unsigned int*)(unsigned long long)g,
      (__attribute__((address_space(3))) unsigned int*)lds_addr,
      16, 0, 0);
}

// ---------------- prep: f32 -> NORMALIZED bf16 (row/||row||) ----------------
__global__ __launch_bounds__(256) void prep_kernel(
    const float* __restrict__ sup, const float* __restrict__ tgt,
    u16* __restrict__ Abf, u16* __restrict__ Bbf)
{
  int w = (int)((blockIdx.x * blockDim.x + threadIdx.x) >> 6);
  int lane = threadIdx.x & 63;
  if (w >= QT + STF) return;
  bool isQ = (w < QT);
  int row = isQ ? w : (w - QT);
  const float* src = (isQ ? tgt : sup) + (size_t)row * DN + lane * 8;
  f32x4 x0 = *(const f32x4*)src;
  f32x4 x1 = *(const f32x4*)(src + 4);
  float ss = 0.f;
  #pragma unroll
  for (int i = 0; i < 4; ++i) { ss += x0[i]*x0[i]; ss += x1[i]*x1[i]; }
  #pragma unroll
  for (int off = 32; off; off >>= 1) ss += __shfl_xor(ss, off);
  float inv = __builtin_amdgcn_rsqf(ss);
  u16x8 o;
  #pragma unroll
  for (int i = 0; i < 4; ++i) { o[i] = f2bf(x0[i]*inv); o[i+4] = f2bf(x1[i]*inv); }
  u16* dst = (isQ ? Abf : Bbf) + (size_t)row * DN + lane * 8;
  *(u16x8*)dst = o;
}

// ---------------- fused: 128x64 MFMA GEMM (4 waves) -> LDS ed-tiles -> DP ----------
// 8 q x 4 s per block = 32 pairs x 2 dirs = 64 tasks x 512B = 32KB dt.
// GEMM: BK=32 double-buffer 2x12KB (A 8KB + B 4KB), union with dt -> 32KB LDS total.
// acc[4][2] = 32 regs so the WHOLE kernel fits 128 unified regs -> 4 waves/SIMD
// -> 4 blocks/CU. 2048 blocks = 8 generations/CU; cross-block phase overlap hides
// vmcnt stalls, barriers, and the 1-wave DP phase.
__global__ __launch_bounds__(256, 4) void fused_kernel(
    const u16* __restrict__ Abf, const u16* __restrict__ Bbf,
    float* __restrict__ out)
{
  __shared__ __align__(128) char smem[32768];
  const int t = threadIdx.x;
  // XCD swizzle: 2048 blocks, 256 consecutive work-ids per XCD
  const int bid = blockIdx.x;
  const int wsw = (bid & 7) * 256 + (bid >> 3);
  const int bx = wsw & 31, by = wsw >> 5;      // 32 s-tiles x 64 q-tiles
  const int m0 = by * 128;   // query-frame base
  const int n0 = bx * 64;    // support-frame base
  const int wave = t >> 6, lane = t & 63;
  const int wr = wave >> 1, wc = wave & 1;
  const int lhi = lane >> 4, llo = lane & 15;

  const unsigned sbase = (unsigned)(unsigned long long)(void*)smem;

  // staging: 3 gld16/thread/tile. A: 128 rows x 64B (2 instr/wave), B: 64 rows x 64B (1).
  // lane -> row lane>>2; phys granule lane&3 holds logical (lane&3)^((lane>>2)&3).
  const int rsub = lane >> 2;
  const int lg = (lane & 3) ^ (rsub & 3);
  const int rA0 = (wave)*16 + rsub;        // instr 0: row blocks 0..3
  const int rA1 = (4 + wave)*16 + rsub;    // instr 1: row blocks 4..7
  const int rB  = wave*16 + rsub;
  const u16* pA0 = Abf + (size_t)(m0 + rA0) * DN + lg*8;
  const u16* pA1 = Abf + (size_t)(m0 + rA1) * DN + lg*8;
  const u16* pB0 = Bbf + (size_t)(n0 + rB) * DN + lg*8;
  const unsigned ldsA0 = __builtin_amdgcn_readfirstlane(sbase + (unsigned)(wave*1024));
  const unsigned ldsA1 = __builtin_amdgcn_readfirstlane(sbase + (unsigned)((4+wave)*1024));
  const unsigned ldsB0 = __builtin_amdgcn_readfirstlane(sbase + 8192u + (unsigned)(wave*1024));

  f32x4 acc[4][2] = {};

  auto STAGE = [&](int sel, int koff) {
    unsigned bo = (unsigned)sel * 12288u;
    gld16(pA0 + koff, ldsA0 + bo);
    gld16(pA1 + koff, ldsA1 + bo);
    gld16(pB0 + koff, ldsB0 + bo);
  };
  auto COMPUTE = [&](int sel) {
    const char* ba = smem + sel * 12288;
    const char* bb = ba + 8192;
    const int pg = (lhi ^ (llo & 3)) << 4;
    bf16x8 af[4], bfr[2];
    #pragma unroll
    for (int mi = 0; mi < 4; ++mi)
      af[mi] = *(const bf16x8*)(ba + (wr*64 + mi*16 + llo)*64 + pg);
    #pragma unroll
    for (int ni = 0; ni < 2; ++ni)
      bfr[ni] = *(const bf16x8*)(bb + (wc*32 + ni*16 + llo)*64 + pg);
    __builtin_amdgcn_s_setprio(1);
    #pragma unroll
    for (int mi = 0; mi < 4; ++mi)
      #pragma unroll
      for (int ni = 0; ni < 2; ++ni)
        acc[mi][ni] = __builtin_amdgcn_mfma_f32_16x16x32_bf16(af[mi], bfr[ni], acc[mi][ni], 0, 0, 0);
    __builtin_amdgcn_s_setprio(0);
  };

  STAGE(0, 0);
  #pragma unroll 1
  for (int it = 0; it < 16; ++it) {
    if (it < 15) {
      STAGE((it + 1) & 1, (it + 1) * 32);
      asm volatile("s_waitcnt vmcnt(3)" ::: "memory");  // own tile-it loads done
    } else {
      asm volatile("s_waitcnt vmcnt(0)" ::: "memory");
    }
    __builtin_amdgcn_s_barrier();                        // all waves' tile-it loads done
    asm volatile("" ::: "memory");
    COMPUTE(it & 1);
    asm volatile("" ::: "memory");
    __builtin_amdgcn_s_barrier();                        // readers done before overwrite
  }
  __syncthreads();  // smem about to be reused as dt

  // ---- epilogue: acc -> ed(bf16) -> dt, both orientations; acc dies here ----
  // dt element (l,m) of task T: T*512 + ((l*32+m*2) ^ ((l&12)<<3) ^ ((T&31)<<4))
  {
    const int ts = llo;
    #pragma unroll
    for (int ni = 0; ni < 2; ++ni) {
      int sloc = wc*2 + ni;
      #pragma unroll
      for (int mi = 0; mi < 4; ++mi) {
        int qq = wr*4 + mi;
        int T0 = (qq*4 + sloc) * 2;
        int T1 = T0 + 1;
        int swz0 = (T0 & 31) << 4, swz1 = (T1 & 31) << 4;
        u16x4 pk;
        #pragma unroll
        for (int j = 0; j < 4; ++j) {
          int tq = lhi*4 + j;
          float ed = EXP2F(fmaf(acc[mi][ni][j], KEXP, -KEXP));
          u16 e16 = f2bf(ed);
          pk[j] = e16;
          *(u16*)(smem + T0*512 + ((tq*32 + ts*2) ^ ((tq&12)<<3) ^ swz0)) = e16;
        }
        *(u16x4*)(smem + T1*512 + ((ts*32 + lhi*8) ^ ((ts&12)<<3) ^ swz1)) = pk;
      }
    }
  }
  __syncthreads();

  // ---- exp-domain DP, one task per lane (wave 0 only; cross-block overlap covers) ----
  if (t < 64) {
    const char* tb = smem + t * 512;
    const int swz = (t & 31) << 4;
    float F[18];
    {
      u16x8 g0 = *(const u16x8*)(tb + (0 ^ swz));
      u16x8 g1 = *(const u16x8*)(tb + (16 ^ swz));
      float c = 1.0f;
      F[0] = 1.0f;
      #pragma unroll
      for (int m = 1; m <= 8; ++m)  { c *= bf2f(g0[m-1]); F[m] = c; }
      #pragma unroll
      for (int m = 9; m <= 16; ++m) { c *= bf2f(g1[m-9]); F[m] = c; }
      F[17] = c;
    }
    u16x8 h0 = *(const u16x8*)(tb + ((32 ^ ((1&12)<<3)) ^ swz));
    u16x8 h1 = *(const u16x8*)(tb + (((32+16) ^ ((1&12)<<3)) ^ swz));
    float rowc = 1.0f;
    #pragma unroll 1
    for (int l = 1; l < 16; ++l) {
      u16x8 n0v, n1v;
      if (l < 15) {
        int lb = (l+1)*32, lx = ((l+1)&12)<<3;
        n0v = *(const u16x8*)(tb + ((lb ^ lx) ^ swz));
        n1v = *(const u16x8*)(tb + (((lb+16) ^ lx) ^ swz));
      }
      rowc *= K2;
      float e[16];
      #pragma unroll
      for (int m = 0; m < 8; ++m)  e[m]   = bf2f(h0[m]);
      #pragma unroll
      for (int m = 0; m < 8; ++m)  e[m+8] = bf2f(h1[m]);
      float c[18];
      c[1] = e[0]*K2*(F[0] + F[1]);            // edge m=1: 3 preds
      #pragma unroll
      for (int m = 2; m <= 16; ++m) c[m] = e[m-1]*K2*F[m-1];
      c[17] = K2*(F[16] + F[17]);              // edge m=17: 3 preds, ed=1
      F[0] = rowc;
      #pragma unroll
      for (int m = 1; m <= 16; ++m) F[m] = fmaf(e[m-1], F[m-1], c[m]);
      F[17] = F[16] + c[17];
      h0 = n0v; h1 = n1v;
    }
    float res = 15.0f - CLOG * LOG2F(F[17]);
    float other = __shfl_xor(res, 1);
    if (!(t & 1)) {
      int pair = t >> 1;                 // 0..31
      int qq = pair >> 2, sl = pair & 3;
      out[(size_t)(by*8 + qq) * SN + bx*4 + sl] = res + other;
    }
  }
}

// ---------------- launch ----------------
extern "C" void kernel_launch(void* const* d_in, const int* in_sizes, int n_in,
                              void* d_out, int out_size, void* d_ws, size_t ws_size,
                              hipStream_t stream)
{
  const float* sup = (const float*)d_in[0];  // [128,16,512]
  const float* tgt = (const float*)d_in[1];  // [512,16,512]
  float* out = (float*)d_out;                // [512,128]
  char* ws = (char*)d_ws;

  u16* Abf = (u16*)(ws);                     // 8192*512*2 = 8,388,608
  u16* Bbf = (u16*)(ws + 8388608);           // 2048*512*2 = 2,097,152

  prep_kernel<<<dim3((QT + STF) / 4), dim3(256), 0, stream>>>(sup, tgt, Abf, Bbf);
  fused_kernel<<<dim3(2048), dim3(256), 0, stream>>>(Abf, Bbf, out);
}

// Round 11
// 42.637 us; speedup vs baseline: 1.1095x; 1.1095x over previous
//
#include <hip/hip_runtime.h>

typedef unsigned short u16;
typedef __attribute__((ext_vector_type(4))) unsigned short u16x4;
typedef __attribute__((ext_vector_type(8))) unsigned short u16x8;
typedef __attribute__((ext_vector_type(8))) short bf16x8;
typedef __attribute__((ext_vector_type(4))) float f32x4;

#define QN 512
#define SN 128
#define DN 512
#define QT 8192   /* query frames */
#define STF 2048  /* support frames */

#if __has_builtin(__builtin_amdgcn_exp2f)
#define EXP2F __builtin_amdgcn_exp2f
#else
#define EXP2F exp2f
#endif
#if __has_builtin(__builtin_amdgcn_logf)
#define LOG2F __builtin_amdgcn_logf
#else
#define LOG2F log2f
#endif

#define KEXP 2.8853900817779268f   /* 1/(lbda*ln2), lbda=0.5 */
#define CLOG 0.34657359027997264f  /* lbda*ln2 */
#define K2   7.38905609893065f     /* exp(1/lbda) = e^2 */
#define BUFSZ 49152u               /* A 32KB + B 16KB per K=64 tile */

__device__ __forceinline__ u16 f2bf(float f){
  union { float f; unsigned int u; } v; v.f = f;
  unsigned int u = v.u;
  unsigned int r = (u + 0x7fffu + ((u >> 16) & 1u)) >> 16;
  return (u16)r;
}
__device__ __forceinline__ float bf2f(u16 v){
  union { unsigned int u; float f; } x; x.u = ((unsigned int)v) << 16; return x.f;
}

__device__ __forceinline__ void gld16(const void* g, unsigned lds_addr){
  __builtin_amdgcn_global_load_lds(
      (const __attribute__((address_space(1))) unsigned int*)(unsigned long long)g,
      (__attribute__((address_space(3))) unsigned int*)lds_addr,
      16, 0, 0);
}

// ---------------- prep: f32 -> NORMALIZED bf16 (row/||row||) ----------------
__global__ __launch_bounds__(256) void prep_kernel(
    const float* __restrict__ sup, const float* __restrict__ tgt,
    u16* __restrict__ Abf, u16* __restrict__ Bbf)
{
  int w = (int)((blockIdx.x * blockDim.x + threadIdx.x) >> 6);
  int lane = threadIdx.x & 63;
  if (w >= QT + STF) return;
  bool isQ = (w < QT);
  int row = isQ ? w : (w - QT);
  const float* src = (isQ ? tgt : sup) + (size_t)row * DN + lane * 8;
  f32x4 x0 = *(const f32x4*)src;
  f32x4 x1 = *(const f32x4*)(src + 4);
  float ss = 0.f;
  #pragma unroll
  for (int i = 0; i < 4; ++i) { ss += x0[i]*x0[i]; ss += x1[i]*x1[i]; }
  #pragma unroll
  for (int off = 32; off; off >>= 1) ss += __shfl_xor(ss, off);
  float inv = __builtin_amdgcn_rsqf(ss);
  u16x8 o;
  #pragma unroll
  for (int i = 0; i < 4; ++i) { o[i] = f2bf(x0[i]*inv); o[i+4] = f2bf(x1[i]*inv); }
  u16* dst = (isQ ? Abf : Bbf) + (size_t)row * DN + lane * 8;
  *(u16x8*)dst = o;
}

// ---------------- fused: 256x128 GEMM, BK=64 (8 iters) -> 128KB dt -> one DP ----------
// 16q x 8s = 128 pairs x 2 dirs = 256 tasks x 512B = 128KB dt, overlaid on the
// 2 x 48KB staging buffers. LDS total 131072 (proven size). 8 waves; wave tile 64x64.
// Per iter/wave: 6 gld16 (A 4 + B 2), 16 ds_read_b128, 32 MFMA; vmcnt(6); 2 barriers.
// DP: 256 tasks on 8 waves x 32 active lanes (2 chains/SIMD hide the serial fma chain).
__global__ __launch_bounds__(512, 2) void fused_kernel(
    const u16* __restrict__ Abf, const u16* __restrict__ Bbf,
    float* __restrict__ out)
{
  __shared__ __align__(128) char smem[131072];
  const int t = threadIdx.x;
  // XCD swizzle: 512 blocks, 64 consecutive work-ids per XCD
  const int bid = blockIdx.x;
  const int wsw = (bid & 7) * 64 + (bid >> 3);
  const int bx = wsw & 15, by = wsw >> 4;
  const int m0 = by * 256;   // query-frame base
  const int n0 = bx * 128;   // support-frame base
  const int wave = t >> 6, lane = t & 63;
  const int wr = wave >> 1, wc = wave & 1;
  const int lhi = lane >> 4, llo = lane & 15;

  const unsigned sbase = (unsigned)(unsigned long long)(void*)smem;

  // staging: row = 128B (K=64). gld16 covers 8 rows x 8 granules; lane>>3 = row-sub,
  // lane&7 = phys granule; source logical granule = phys ^ (row&7) (row&7 == lane>>3).
  const int rsub = lane >> 3;
  const int lg = (lane & 7) ^ rsub;
  const u16* pA[4]; unsigned ldsA[4];
  #pragma unroll
  for (int i = 0; i < 4; ++i) {
    int row = wave*32 + i*8 + rsub;                       // A: 256 rows, 32/wave
    pA[i] = Abf + (size_t)(m0 + row) * DN + lg*8;
    ldsA[i] = __builtin_amdgcn_readfirstlane(sbase + (unsigned)(wave*4096 + i*1024));
  }
  const u16* pB[2]; unsigned ldsB[2];
  #pragma unroll
  for (int i = 0; i < 2; ++i) {
    int row = wave*16 + i*8 + rsub;                       // B: 128 rows, 16/wave
    pB[i] = Bbf + (size_t)(n0 + row) * DN + lg*8;
    ldsB[i] = __builtin_amdgcn_readfirstlane(sbase + 32768u + (unsigned)(wave*2048 + i*1024));
  }

  f32x4 acc[4][4] = {};

  auto STAGE = [&](int sel, int koff) {
    unsigned bo = (unsigned)sel * BUFSZ;
    #pragma unroll
    for (int i = 0; i < 4; ++i) gld16(pA[i] + koff, ldsA[i] + bo);
    #pragma unroll
    for (int i = 0; i < 2; ++i) gld16(pB[i] + koff, ldsB[i] + bo);
  };
  auto COMPUTE = [&](int sel) {
    const char* ba = smem + sel * BUFSZ;
    const char* bb = ba + 32768;
    #pragma unroll
    for (int kk = 0; kk < 2; ++kk) {
      const int pg = ((kk*4 + lhi) ^ (llo & 7)) << 4;     // swizzled 16B granule
      bf16x8 af[4], bfr[4];
      #pragma unroll
      for (int mi = 0; mi < 4; ++mi)
        af[mi] = *(const bf16x8*)(ba + (wr*64 + mi*16 + llo)*128 + pg);
      #pragma unroll
      for (int ni = 0; ni < 4; ++ni)
        bfr[ni] = *(const bf16x8*)(bb + (wc*64 + ni*16 + llo)*128 + pg);
      __builtin_amdgcn_s_setprio(1);
      #pragma unroll
      for (int mi = 0; mi < 4; ++mi)
        #pragma unroll
        for (int ni = 0; ni < 4; ++ni)
          acc[mi][ni] = __builtin_amdgcn_mfma_f32_16x16x32_bf16(af[mi], bfr[ni], acc[mi][ni], 0, 0, 0);
      __builtin_amdgcn_s_setprio(0);
    }
  };

  STAGE(0, 0);
  #pragma unroll 1
  for (int it = 0; it < 8; ++it) {
    if (it < 7) {
      STAGE((it + 1) & 1, (it + 1) * 64);
      asm volatile("s_waitcnt vmcnt(6)" ::: "memory");   // own tile-it loads done
    } else {
      asm volatile("s_waitcnt vmcnt(0)" ::: "memory");
    }
    __builtin_amdgcn_s_barrier();                         // all waves' tile-it ready
    asm volatile("" ::: "memory");
    COMPUTE(it & 1);
    asm volatile("" ::: "memory");
    __builtin_amdgcn_s_barrier();                         // readers done before overwrite
  }
  __syncthreads();  // smem about to be reused as dt (128KB, 256 tasks)

  // ---- single epilogue: all 8 waves dump acc -> ed(bf16) -> dt; acc dies here ----
  // dt element (l,m) of task T: T*512 + ((l*32+m*2) ^ ((l&12)<<3) ^ ((T&31)<<4))
  {
    const int ts = llo;
    #pragma unroll
    for (int ni = 0; ni < 4; ++ni) {
      int sloc = wc*4 + ni;                 // 0..7
      #pragma unroll
      for (int mi = 0; mi < 4; ++mi) {
        int qq = wr*4 + mi;                 // 0..15
        int T0 = (qq*8 + sloc) * 2;
        int T1 = T0 + 1;
        int swz0 = (T0 & 31) << 4, swz1 = (T1 & 31) << 4;
        u16x4 pk;
        #pragma unroll
        for (int j = 0; j < 4; ++j) {
          int tq = lhi*4 + j;
          float ed = EXP2F(fmaf(acc[mi][ni][j], KEXP, -KEXP));
          u16 e16 = f2bf(ed);
          pk[j] = e16;
          *(u16*)(smem + T0*512 + ((tq*32 + ts*2) ^ ((tq&12)<<3) ^ swz0)) = e16;
        }
        *(u16x4*)(smem + T1*512 + ((ts*32 + lhi*8) ^ ((ts&12)<<3) ^ swz1)) = pk;
      }
    }
  }
  __syncthreads();

  // ---- exp-domain DP: 256 tasks, 8 waves x 32 active lanes ----
  if (lane < 32) {
    const int task = wave*32 + lane;        // 0..255
    const char* tb = smem + task * 512;
    const int swz = (task & 31) << 4;
    float F[18];
    {
      u16x8 g0 = *(const u16x8*)(tb + (0 ^ swz));
      u16x8 g1 = *(const u16x8*)(tb + (16 ^ swz));
      float c = 1.0f;
      F[0] = 1.0f;
      #pragma unroll
      for (int m = 1; m <= 8; ++m)  { c *= bf2f(g0[m-1]); F[m] = c; }
      #pragma unroll
      for (int m = 9; m <= 16; ++m) { c *= bf2f(g1[m-9]); F[m] = c; }
      F[17] = c;
    }
    u16x8 h0 = *(const u16x8*)(tb + ((32 ^ ((1&12)<<3)) ^ swz));
    u16x8 h1 = *(const u16x8*)(tb + (((32+16) ^ ((1&12)<<3)) ^ swz));
    float rowc = 1.0f;
    #pragma unroll 1
    for (int l = 1; l < 16; ++l) {
      u16x8 n0v, n1v;
      if (l < 15) {
        int lb = (l+1)*32, lx = ((l+1)&12)<<3;
        n0v = *(const u16x8*)(tb + ((lb ^ lx) ^ swz));
        n1v = *(const u16x8*)(tb + (((lb+16) ^ lx) ^ swz));
      }
      rowc *= K2;
      float e[16];
      #pragma unroll
      for (int m = 0; m < 8; ++m)  e[m]   = bf2f(h0[m]);
      #pragma unroll
      for (int m = 0; m < 8; ++m)  e[m+8] = bf2f(h1[m]);
      float c[18];
      c[1] = e[0]*K2*(F[0] + F[1]);            // edge m=1: 3 preds
      #pragma unroll
      for (int m = 2; m <= 16; ++m) c[m] = e[m-1]*K2*F[m-1];
      c[17] = K2*(F[16] + F[17]);              // edge m=17: 3 preds, ed=1
      F[0] = rowc;
      #pragma unroll
      for (int m = 1; m <= 16; ++m) F[m] = fmaf(e[m-1], F[m-1], c[m]);
      F[17] = F[16] + c[17];
      h0 = n0v; h1 = n1v;
    }
    float res = 15.0f - CLOG * LOG2F(F[17]);
    float other = __shfl_xor(res, 1);
    if (!(task & 1)) {
      int pair = task >> 1;                // 0..127
      int qq = pair >> 3, sl = pair & 7;
      out[(size_t)(by*16 + qq) * SN + bx*8 + sl] = res + other;
    }
  }
}

// ---------------- launch ----------------
extern "C" void kernel_launch(void* const* d_in, const int* in_sizes, int n_in,
                              void* d_out, int out_size, void* d_ws, size_t ws_size,
                              hipStream_t stream)
{
  const float* sup = (const float*)d_in[0];  // [128,16,512]
  const float* tgt = (const float*)d_in[1];  // [512,16,512]
  float* out = (float*)d_out;                // [512,128]
  char* ws = (char*)d_ws;

  u16* Abf = (u16*)(ws);                     // 8192*512*2 = 8,388,608
  u16* Bbf = (u16*)(ws + 8388608);           // 2048*512*2 = 2,097,152

  prep_kernel<<<dim3((QT + STF) / 4), dim3(256), 0, stream>>>(sup, tgt, Abf, Bbf);
  fused_kernel<<<dim3(512), dim3(512), 0, stream>>>(Abf, Bbf, out);
}

// Round 13
// 41.456 us; speedup vs baseline: 1.1411x; 1.0285x over previous
//
#include <hip/hip_runtime.h>

typedef unsigned short u16;
typedef __attribute__((ext_vector_type(4))) unsigned short u16x4;
typedef __attribute__((ext_vector_type(8))) unsigned short u16x8;
typedef __attribute__((ext_vector_type(8))) short bf16x8;
typedef __attribute__((ext_vector_type(4))) float f32x4;

#define QN 512
#define SN 128
#define DN 512
#define QT 8192   /* query frames */
#define STF 2048  /* support frames */

#if __has_builtin(__builtin_amdgcn_exp2f)
#define EXP2F __builtin_amdgcn_exp2f
#else
#define EXP2F exp2f
#endif
#if __has_builtin(__builtin_amdgcn_logf)
#define LOG2F __builtin_amdgcn_logf
#else
#define LOG2F log2f
#endif

#define KEXP 2.8853900817779268f   /* 1/(lbda*ln2), lbda=0.5 */
#define CLOG 0.34657359027997264f  /* lbda*ln2 */
#define K2   7.38905609893065f     /* exp(1/lbda) = e^2 */
#define BUFSZ 49152u               /* A 32KB + B 16KB per K=64 tile */

__device__ __forceinline__ u16 f2bf(float f){
  union { float f; unsigned int u; } v; v.f = f;
  unsigned int u = v.u;
  unsigned int r = (u + 0x7fffu + ((u >> 16) & 1u)) >> 16;
  return (u16)r;
}
__device__ __forceinline__ float bf2f(u16 v){
  union { unsigned int u; float f; } x; x.u = ((unsigned int)v) << 16; return x.f;
}

__device__ __forceinline__ void gld16(const void* g, unsigned lds_addr){
  __builtin_amdgcn_global_load_lds(
      (const __attribute__((address_space(1))) unsigned int*)(unsigned long long)g,
      (__attribute__((address_space(3))) unsigned int*)lds_addr,
      16, 0, 0);
}

// ---------------- prep: f32 -> NORMALIZED bf16 (row/||row||) ----------------
__global__ __launch_bounds__(256) void prep_kernel(
    const float* __restrict__ sup, const float* __restrict__ tgt,
    u16* __restrict__ Abf, u16* __restrict__ Bbf)
{
  int w = (int)((blockIdx.x * blockDim.x + threadIdx.x) >> 6);
  int lane = threadIdx.x & 63;
  if (w >= QT + STF) return;
  bool isQ = (w < QT);
  int row = isQ ? w : (w - QT);
  const float* src = (isQ ? tgt : sup) + (size_t)row * DN + lane * 8;
  f32x4 x0 = *(const f32x4*)src;
  f32x4 x1 = *(const f32x4*)(src + 4);
  float ss = 0.f;
  #pragma unroll
  for (int i = 0; i < 4; ++i) { ss += x0[i]*x0[i]; ss += x1[i]*x1[i]; }
  #pragma unroll
  for (int off = 32; off; off >>= 1) ss += __shfl_xor(ss, off);
  float inv = __builtin_amdgcn_rsqf(ss);
  u16x8 o;
  #pragma unroll
  for (int i = 0; i < 4; ++i) { o[i] = f2bf(x0[i]*inv); o[i+4] = f2bf(x1[i]*inv); }
  u16* dst = (isQ ? Abf : Bbf) + (size_t)row * DN + lane * 8;
  *(u16x8*)dst = o;
}

// ---------------- fused: 256x128 GEMM, BK=64, TRIPLE-buffer depth-2 pipeline ----------
// 16q x 8s = 128 pairs x 2 dirs = 256 tasks x 512B = 128KB dt, overlaid on the
// 3 x 48KB staging buffers (147456 B LDS total). 8 waves; wave tile 64x64.
// Schedule per K-tile it: vmcnt(6) [tile-it loads, issued 2 tiles ago] -> ONE barrier
// -> {8 ds_read + 16 MFMA} x2 + stage tile it+2 into buf (it+2)%3 between halves.
// vmcnt ledger: top-of-iter 12 outstanding (tiles it, it+1); vmcnt(6) retires tile it.
// Hazard: buf (it+2)%3 == buf (it-1)%3 was fully read before barrier(it) (lgkmcnt
// precedes the MFMAs which precede the barrier) -> write-after-read safe.
__global__ __launch_bounds__(512, 2) void fused_kernel(
    const u16* __restrict__ Abf, const u16* __restrict__ Bbf,
    float* __restrict__ out)
{
  __shared__ __align__(128) char smem[147456];
  const int t = threadIdx.x;
  // XCD swizzle: 512 blocks, 64 consecutive work-ids per XCD
  const int bid = blockIdx.x;
  const int wsw = (bid & 7) * 64 + (bid >> 3);
  const int bx = wsw & 15, by = wsw >> 4;
  const int m0 = by * 256;   // query-frame base
  const int n0 = bx * 128;   // support-frame base
  const int wave = t >> 6, lane = t & 63;
  const int wr = wave >> 1, wc = wave & 1;
  const int lhi = lane >> 4, llo = lane & 15;

  const unsigned sbase = (unsigned)(unsigned long long)(void*)smem;

  // staging: row = 128B (K=64). gld16 covers 8 rows x 8 granules; lane>>3 = row-sub,
  // lane&7 = phys granule; source logical granule = phys ^ (row&7) (row&7 == lane>>3).
  const int rsub = lane >> 3;
  const int lg = (lane & 7) ^ rsub;
  const u16* pA[4]; unsigned ldsA[4];
  #pragma unroll
  for (int i = 0; i < 4; ++i) {
    int row = wave*32 + i*8 + rsub;                       // A: 256 rows, 32/wave
    pA[i] = Abf + (size_t)(m0 + row) * DN + lg*8;
    ldsA[i] = __builtin_amdgcn_readfirstlane(sbase + (unsigned)(wave*4096 + i*1024));
  }
  const u16* pB[2]; unsigned ldsB[2];
  #pragma unroll
  for (int i = 0; i < 2; ++i) {
    int row = wave*16 + i*8 + rsub;                       // B: 128 rows, 16/wave
    pB[i] = Bbf + (size_t)(n0 + row) * DN + lg*8;
    ldsB[i] = __builtin_amdgcn_readfirstlane(sbase + 32768u + (unsigned)(wave*2048 + i*1024));
  }

  f32x4 acc[4][4] = {};

  auto STAGE = [&](unsigned bo, int koff) {
    #pragma unroll
    for (int i = 0; i < 4; ++i) gld16(pA[i] + koff, ldsA[i] + bo);
    #pragma unroll
    for (int i = 0; i < 2; ++i) gld16(pB[i] + koff, ldsB[i] + bo);
  };
  auto COMPUTE_HALF = [&](const char* ba, const char* bb, int kk) {
    const int pg = ((kk*4 + lhi) ^ (llo & 7)) << 4;       // swizzled 16B granule
    bf16x8 af[4], bfr[4];
    #pragma unroll
    for (int mi = 0; mi < 4; ++mi)
      af[mi] = *(const bf16x8*)(ba + (wr*64 + mi*16 + llo)*128 + pg);
    #pragma unroll
    for (int ni = 0; ni < 4; ++ni)
      bfr[ni] = *(const bf16x8*)(bb + (wc*64 + ni*16 + llo)*128 + pg);
    __builtin_amdgcn_s_setprio(1);
    #pragma unroll
    for (int mi = 0; mi < 4; ++mi)
      #pragma unroll
      for (int ni = 0; ni < 4; ++ni)
        acc[mi][ni] = __builtin_amdgcn_mfma_f32_16x16x32_bf16(af[mi], bfr[ni], acc[mi][ni], 0, 0, 0);
    __builtin_amdgcn_s_setprio(0);
  };

  // prologue: tiles 0 and 1 into bufs 0,1 (12 loads outstanding)
  STAGE(0u, 0);
  STAGE(BUFSZ, 64);
  unsigned bsel = 0;  // (it % 3) * BUFSZ
  #pragma unroll 1
  for (int it = 0; it < 8; ++it) {
    if (it < 7) {
      asm volatile("s_waitcnt vmcnt(6)" ::: "memory");   // tile-it's 6 loads done
    } else {
      asm volatile("s_waitcnt vmcnt(0)" ::: "memory");
    }
    __builtin_amdgcn_s_barrier();     // all waves: tile-it DMA done & tile-(it-1) reads done
    asm volatile("" ::: "memory");
    const char* ba = smem + bsel;
    const char* bb = ba + 32768;
    unsigned nsel = bsel + 2*BUFSZ; if (nsel >= 3*BUFSZ) nsel -= 3*BUFSZ;  // (it+2)%3
    COMPUTE_HALF(ba, bb, 0);
    if (it < 6) STAGE(nsel, (it + 2) * 64);              // stage tile it+2 (depth-2)
    COMPUTE_HALF(ba, bb, 1);
    asm volatile("" ::: "memory");
    bsel += BUFSZ; if (bsel >= 3*BUFSZ) bsel = 0;
  }
  __syncthreads();  // smem about to be reused as dt (128KB, 256 tasks)

  // ---- single epilogue: all 8 waves dump acc -> ed(bf16) -> dt; acc dies here ----
  // dt element (l,m) of task T: T*512 + ((l*32+m*2) ^ ((l&12)<<3) ^ ((T&31)<<4))
  {
    const int ts = llo;
    #pragma unroll
    for (int ni = 0; ni < 4; ++ni) {
      int sloc = wc*4 + ni;                 // 0..7
      #pragma unroll
      for (int mi = 0; mi < 4; ++mi) {
        int qq = wr*4 + mi;                 // 0..15
        int T0 = (qq*8 + sloc) * 2;
        int T1 = T0 + 1;
        int swz0 = (T0 & 31) << 4, swz1 = (T1 & 31) << 4;
        u16x4 pk;
        #pragma unroll
        for (int j = 0; j < 4; ++j) {
          int tq = lhi*4 + j;
          float ed = EXP2F(fmaf(acc[mi][ni][j], KEXP, -KEXP));
          u16 e16 = f2bf(ed);
          pk[j] = e16;
          *(u16*)(smem + T0*512 + ((tq*32 + ts*2) ^ ((tq&12)<<3) ^ swz0)) = e16;
        }
        *(u16x4*)(smem + T1*512 + ((ts*32 + lhi*8) ^ ((ts&12)<<3) ^ swz1)) = pk;
      }
    }
  }
  __syncthreads();

  // ---- exp-domain DP: 256 tasks, 8 waves x 32 active lanes ----
  if (lane < 32) {
    const int task = wave*32 + lane;        // 0..255
    const char* tb = smem + task * 512;
    const int swz = (task & 31) << 4;
    float F[18];
    {
      u16x8 g0 = *(const u16x8*)(tb + (0 ^ swz));
      u16x8 g1 = *(const u16x8*)(tb + (16 ^ swz));
      float c = 1.0f;
      F[0] = 1.0f;
      #pragma unroll
      for (int m = 1; m <= 8; ++m)  { c *= bf2f(g0[m-1]); F[m] = c; }
      #pragma unroll
      for (int m = 9; m <= 16; ++m) { c *= bf2f(g1[m-9]); F[m] = c; }
      F[17] = c;
    }
    u16x8 h0 = *(const u16x8*)(tb + ((32 ^ ((1&12)<<3)) ^ swz));
    u16x8 h1 = *(const u16x8*)(tb + (((32+16) ^ ((1&12)<<3)) ^ swz));
    float rowc = 1.0f;
    #pragma unroll 1
    for (int l = 1; l < 16; ++l) {
      u16x8 n0v, n1v;
      if (l < 15) {
        int lb = (l+1)*32, lx = ((l+1)&12)<<3;
        n0v = *(const u16x8*)(tb + ((lb ^ lx) ^ swz));
        n1v = *(const u16x8*)(tb + (((lb+16) ^ lx) ^ swz));
      }
      rowc *= K2;
      float e[16];
      #pragma unroll
      for (int m = 0; m < 8; ++m)  e[m]   = bf2f(h0[m]);
      #pragma unroll
      for (int m = 0; m < 8; ++m)  e[m+8] = bf2f(h1[m]);
      float c[18];
      c[1] = e[0]*K2*(F[0] + F[1]);            // edge m=1: 3 preds
      #pragma unroll
      for (int m = 2; m <= 16; ++m) c[m] = e[m-1]*K2*F[m-1];
      c[17] = K2*(F[16] + F[17]);              // edge m=17: 3 preds, ed=1
      F[0] = rowc;
      #pragma unroll
      for (int m = 1; m <= 16; ++m) F[m] = fmaf(e[m-1], F[m-1], c[m]);
      F[17] = F[16] + c[17];
      h0 = n0v; h1 = n1v;
    }
    float res = 15.0f - CLOG * LOG2F(F[17]);
    float other = __shfl_xor(res, 1);
    if (!(task & 1)) {
      int pair = task >> 1;                // 0..127
      int qq = pair >> 3, sl = pair & 7;
      out[(size_t)(by*16 + qq) * SN + bx*8 + sl] = res + other;
    }
  }
}

// ---------------- launch ----------------
extern "C" void kernel_launch(void* const* d_in, const int* in_sizes, int n_in,
                              void* d_out, int out_size, void* d_ws, size_t ws_size,
                              hipStream_t stream)
{
  const float* sup = (const float*)d_in[0];  // [128,16,512]
  const float* tgt = (const float*)d_in[1];  // [512,16,512]
  float* out = (float*)d_out;                // [512,128]
  char* ws = (char*)d_ws;

  u16* Abf = (u16*)(ws);                     // 8192*512*2 = 8,388,608
  u16* Bbf = (u16*)(ws + 8388608);           // 2048*512*2 = 2,097,152

  prep_kernel<<<dim3((QT + STF) / 4), dim3(256), 0, stream>>>(sup, tgt, Abf, Bbf);
  fused_kernel<<<dim3(512), dim3(512), 0, stream>>>(Abf, Bbf, out);
}